// Round 5
// baseline (3112.933 us; speedup 1.0000x reference)
//
#include <hip/hip_runtime.h>
#include <hip/hip_cooperative_groups.h>
#include <math.h>

namespace cg = cooperative_groups;

typedef unsigned short u16;
typedef unsigned int u32;
typedef short bf16x8 __attribute__((ext_vector_type(8)));
typedef float f32x4 __attribute__((ext_vector_type(4)));

#define PI_F 3.14159265358979323846f

__device__ __forceinline__ float bf2f(u16 u){ union{u32 i; float f;} v; v.i=((u32)u)<<16; return v.f; }
__device__ __forceinline__ u16 f2bf(float f){ union{u32 i; float f;} v; v.f=f; u32 r=v.i+0x7fffu+((v.i>>16)&1u); return (u16)(r>>16); }
__device__ __forceinline__ float sigf(float x){ return 1.0f/(1.0f+expf(-x)); }

// ---------------- pack conv2 weights to bf16 fragment order: wpack[tap][chunk][oc][k=q*8+j] ----------------
__global__ __launch_bounds__(256) void wpack_kernel(const float* __restrict__ w2, u16* __restrict__ wpack)
{
  int e = blockIdx.x*256 + threadIdx.x;   // 36864 = 9*2*64*32
  if (e >= 36864) return;
  int k  = e & 31;
  int oc = (e>>5) & 63;
  int tc = e>>11;            // 0..17
  int tap = tc>>1, c = tc&1;
  int ic = c*32 + k;
  wpack[e] = f2bf(w2[(size_t)(oc*64 + ic)*9 + tap]);
}

// ---------------- pack gate weights wih (512x4096) to bf16 fragment order: wg[kc][n][kidx] ----------------
__global__ __launch_bounds__(256) void wgpack_kernel(const float* __restrict__ wih, u16* __restrict__ wg)
{
  int e = blockIdx.x*256 + threadIdx.x;   // 2097152 = 128*512*32
  int kidx = e & 31;
  int n  = (e>>5) & 511;
  int kc = e>>14;           // 0..127
  wg[e] = f2bf(wih[(size_t)n*4096 + kc*32 + kidx]);
}

// ---------------- conv1: img (B,2,64,64)[ch] f32 -> bf16 NHWC (B,64,64,64ch) ----------------
__global__ __launch_bounds__(256) void conv1_nhwc_kernel(
    const float* __restrict__ imgp, int ch,
    const float* __restrict__ w1, u16* __restrict__ out)
{
  int b = blockIdx.y, tile = blockIdx.x;
  int ty0 = (tile>>2)<<4, tx0 = (tile&3)<<4;
  int tid = threadIdx.x;
  __shared__ float patch[18*18];
  __shared__ float wsm[576];
  const float* ib = imgp + (((size_t)b*2 + ch)<<12);
  for (int e=tid; e<324; e+=256){
    int py = e/18, px = e - py*18;
    int gy = ty0+py-1, gx = tx0+px-1;
    float v = 0.f;
    if (gy>=0 && gy<64 && gx>=0 && gx<64) v = ib[(gy<<6)+gx];
    patch[e] = v;
  }
  for (int e=tid; e<576; e+=256) wsm[e] = w1[e];
  __syncthreads();
  int ty = tid>>4, tx = tid&15;
  float p[9];
  #pragma unroll
  for (int ky=0;ky<3;ky++)
    #pragma unroll
    for (int kx=0;kx<3;kx++) p[ky*3+kx] = patch[(ty+ky)*18 + tx+kx];
  u16* ob = out + ((((size_t)b<<12) + ((size_t)(ty0+ty)<<6) + (size_t)(tx0+tx))<<6);
  #pragma unroll
  for (int ocq=0; ocq<8; ocq++){
    u32 w4[4];
    #pragma unroll
    for (int pair=0; pair<4; pair++){
      float a0=0.f, a1=0.f;
      int oc0 = ocq*8 + pair*2;
      #pragma unroll
      for (int k=0;k<9;k++){ a0 += wsm[oc0*9+k]*p[k]; a1 += wsm[(oc0+1)*9+k]*p[k]; }
      w4[pair] = (u32)f2bf(a0) | ((u32)f2bf(a1)<<16);
    }
    ((uint4*)ob)[ocq] = make_uint4(w4[0],w4[1],w4[2],w4[3]);
  }
}

// ---------------- per-channel sum/sumsq over NHWC bf16 buf ----------------
__global__ __launch_bounds__(256) void stats_nhwc_kernel(const u16* __restrict__ buf, float* __restrict__ st)
{
  int tid = threadIdx.x;
  int c8 = (tid&7)*8;
  int pg = tid>>3;                 // 0..31
  size_t p0 = (size_t)blockIdx.x*1024 + pg;
  float s[8], s2[8];
  #pragma unroll
  for (int k=0;k<8;k++){ s[k]=0.f; s2[k]=0.f; }
  for (int it=0; it<32; it++){
    size_t p = p0 + (size_t)it*32;
    uint4 v = *(const uint4*)(buf + (p<<6) + c8);
    u32 rw[4] = {v.x,v.y,v.z,v.w};
    #pragma unroll
    for (int d=0; d<4; d++){
      float f0 = bf2f((u16)(rw[d]&0xffff));
      float f1 = bf2f((u16)(rw[d]>>16));
      s[d*2]   += f0; s2[d*2]   += f0*f0;
      s[d*2+1] += f1; s2[d*2+1] += f1*f1;
    }
  }
  #pragma unroll
  for (int off=32; off>=8; off>>=1){
    #pragma unroll
    for (int k=0;k<8;k++){ s[k] += __shfl_down(s[k], off, 64); s2[k] += __shfl_down(s2[k], off, 64); }
  }
  __shared__ float sm[128];
  if (tid<128) sm[tid]=0.f;
  __syncthreads();
  if ((tid&63) < 8){
    int cb = tid&7;
    #pragma unroll
    for (int k=0;k<8;k++){
      atomicAdd(&sm[cb*8+k], s[k]);
      atomicAdd(&sm[64+cb*8+k], s2[k]);
    }
  }
  __syncthreads();
  if (tid<128) atomicAdd(&st[tid], sm[tid]);
}

// ---------------- BN apply (+optional residual) + ReLU, in-place on NHWC bf16 ----------------
__global__ __launch_bounds__(256) void bnapply_nhwc_kernel(
    u16* __restrict__ buf, const float* __restrict__ st,
    const float* __restrict__ gam, const float* __restrict__ bet,
    const float* __restrict__ imgp, int ch, int addres)
{
  size_t i8 = (size_t)blockIdx.x*256 + threadIdx.x;
  size_t e0 = i8*8;
  int cb = (int)(e0&63);
  size_t pos = e0>>6;
  const float invN = 1.0f/524288.0f;
  float res = 0.f;
  if (addres){
    int b = (int)(pos>>12);
    res = imgp[(((size_t)(b*2+ch))<<12) + (pos&4095)];
  }
  uint4 raw = *(const uint4*)(buf+e0);
  u32 rw[4] = {raw.x, raw.y, raw.z, raw.w};
  u32 ow[4];
  #pragma unroll
  for (int d=0; d<4; d++){
    u32 o = 0;
    #pragma unroll
    for (int h=0; h<2; h++){
      int c = cb + d*2 + h;
      float mean = st[c]*invN;
      float var  = st[64+c]*invN - mean*mean;
      float sc = gam[c]*rsqrtf(var+1e-5f);
      float sh = bet[c] - mean*sc;
      float v = bf2f((u16)((rw[d]>>(16*h))&0xffff))*sc + sh + res;
      v = fmaxf(v, 0.f);
      o |= ((u32)f2bf(v)) << (16*h);
    }
    ow[d] = o;
  }
  *(uint4*)(buf+e0) = make_uint4(ow[0],ow[1],ow[2],ow[3]);
}

// ---------------- conv2 MFMA: NHWC bf16 -> NHWC bf16 ----------------
__global__ __launch_bounds__(256) void conv2_mfma_kernel(
    const u16* __restrict__ in, const u16* __restrict__ wpack, u16* __restrict__ out)
{
  int b = blockIdx.y, tile = blockIdx.x;     // 32 tiles: 8 y-tiles x 4 x-tiles
  int y0 = (tile>>2)*8, x0 = (tile&3)*16;
  int tid = threadIdx.x;
  int w = tid>>6, lane = tid&63;
  int m = lane&15, q = lane>>4;

  __shared__ __align__(16) u16 patch[11520];  // [py10][cq8][px18][j8]

  for (int e=tid; e<1440; e+=256){
    int py = e/144; int rem = e - py*144;
    int px = rem>>3, cq = rem&7;
    int y = y0-1+py, x = x0-1+px;
    uint4 v = make_uint4(0,0,0,0);
    if (y>=0 && y<64 && x>=0 && x<64)
      v = *(const uint4*)(in + ((((size_t)b<<12) + ((size_t)y<<6) + (size_t)x)<<6) + cq*8);
    *(uint4*)(patch + ((((py<<3)+cq)*18 + px)<<3)) = v;
  }
  __syncthreads();

  f32x4 acc[2][4];
  #pragma unroll
  for (int mt=0;mt<2;mt++)
    #pragma unroll
    for (int nt=0;nt<4;nt++) acc[mt][nt] = (f32x4){0.f,0.f,0.f,0.f};

  #pragma unroll
  for (int tap=0; tap<9; tap++){
    const int dy = tap/3, dx = tap%3;
    #pragma unroll
    for (int c=0; c<2; c++){
      const int kk = tap*2 + c;
      bf16x8 bw[4];
      #pragma unroll
      for (int nt=0; nt<4; nt++)
        bw[nt] = *(const bf16x8*)(wpack + (size_t)(kk*64 + nt*16 + m)*32 + q*8);
      #pragma unroll
      for (int mt=0; mt<2; mt++){
        int py = 2*w + mt + dy;
        bf16x8 av = *(const bf16x8*)(patch + ((((py<<3) + (c<<2) + q)*18 + (m+dx))<<3));
        #pragma unroll
        for (int nt=0; nt<4; nt++)
          acc[mt][nt] = __builtin_amdgcn_mfma_f32_16x16x32_bf16(av, bw[nt], acc[mt][nt], 0,0,0);
      }
    }
  }
  __syncthreads();
  u16* etile = patch;                        // reuse: 128px x 64oc bf16 = 16KB
  #pragma unroll
  for (int mt=0; mt<2; mt++){
    int lp = (2*w+mt)*16 + q*4;
    #pragma unroll
    for (int nt=0; nt<4; nt++)
      #pragma unroll
      for (int r=0; r<4; r++)
        etile[(lp+r)*64 + nt*16 + m] = f2bf(acc[mt][nt][r]);
  }
  __syncthreads();
  int lp = tid>>1, half = tid&1;
  int y = y0 + (lp>>4), x = x0 + (lp&15);
  uint4* gdst = (uint4*)(out + ((((size_t)b<<12) + ((size_t)y<<6) + (size_t)x)<<6) + half*32);
  const uint4* lsrc = (const uint4*)(etile + lp*64 + half*32);
  gdst[0] = lsrc[0];
  gdst[1] = lsrc[1];
  gdst[2] = lsrc[2];
  gdst[3] = lsrc[3];
}

// ---------------- glimpser linear + tanh + Cauchy filterbanks (per-lane helper, lane<64) ----------------
__device__ __forceinline__ void compute_params_lane(
    int b, int lane, float h0, float h1,
    const float* __restrict__ gw, const float* __restrict__ gb,
    float* __restrict__ FhT, float* __restrict__ Fw)
{
  float gpv[3];
  #pragma unroll
  for (int k=0;k<3;k++){
    float p = h0*gw[k*128+lane] + h1*gw[k*128+64+lane];
    #pragma unroll
    for (int off=32; off>0; off>>=1) p += __shfl_down(p, off, 64);
    float tot = __shfl(p, 0, 64);
    gpv[k] = tanhf(tot + gb[k]);
  }
  float ad = fabsf(gpv[2]);
  float delta = 8.0f*(1.0f-ad);
  float gamma = expf(1.0f-2.0f*ad);
  float inv_pg = 1.0f/(PI_F*gamma);
  float fi = (float)lane;
  float ctr = 31.5f*(gpv[0]+1.0f);
  float fh[8];
  #pragma unroll
  for (int g=0; g<8; g++){
    float mu = ctr + delta*((float)g - 3.5f);
    float u = (fi - mu)/gamma;
    float f = inv_pg/(1.0f+u*u);
    float s = f;
    #pragma unroll
    for (int off=32; off>0; off>>=1) s += __shfl_down(s, off, 64);
    s = __shfl(s, 0, 64);
    fh[g] = f/(s + 1e-4f);
  }
  float4* o = (float4*)(FhT + (((size_t)b<<6) + lane)*8);
  o[0] = make_float4(fh[0],fh[1],fh[2],fh[3]);
  o[1] = make_float4(fh[4],fh[5],fh[6],fh[7]);
  ctr = 31.5f*(gpv[1]+1.0f);
  #pragma unroll
  for (int wv=0; wv<8; wv++){
    float mu = ctr + delta*((float)wv - 3.5f);
    float u = (fi - mu)/gamma;
    float f = inv_pg/(1.0f+u*u);
    float s = f;
    #pragma unroll
    for (int off=32; off>0; off>>=1) s += __shfl_down(s, off, 64);
    s = __shfl(s, 0, 64);
    Fw[(((size_t)b<<3)+wv)*64 + lane] = f/(s + 1e-4f);
  }
}

__global__ __launch_bounds__(64) void params_kernel(
    const float* __restrict__ Hx,
    const float* __restrict__ gw, const float* __restrict__ gb,
    float* __restrict__ FhT, float* __restrict__ Fw)
{
  int b = blockIdx.x, lane = threadIdx.x;
  compute_params_lane(b, lane, Hx[b*128+lane], Hx[b*128+64+lane], gw, gb, FhT, Fw);
}

__global__ __launch_bounds__(256) void transpose_whh_kernel(
    const float* __restrict__ whh, float* __restrict__ whhT)
{
  int idx = blockIdx.x*256 + threadIdx.x; // 65536 total
  int k = idx>>9, n = idx&511;
  whhT[idx] = whh[n*128 + k];
}

// ================= turn-loop phase device functions (shared by coop + fallback) =================
#define TJ 33      // j-stride in t_lds
#define TG 2113    // g-stride in t_lds (64*33+1)
#define SMEM_FLOATS 9488   // 512 + 520 + 4*2113 = 9484, rounded; 37.9 KB

// phase G: glimpse. blk in [0,256): (b = blk>>1, ch-half = blk&1). 256 threads.
__device__ void glimpse_phase(int blk, int tid, const u16* __restrict__ im,
                              const float* __restrict__ FhT, const float* __restrict__ Fw,
                              u16* __restrict__ flatbf, float* smem)
{
  float* fh_lds = smem;          // 512: [i][g]
  float* fw_lds = smem + 512;    // 8*65: [w][j] padded
  float* t_lds  = smem + 1032;   // 4*TG: [g-half][j*TJ + c]
  int b = blk>>1, ch = blk&1;
  for (int e=tid; e<512; e+=256) fh_lds[e] = FhT[((size_t)b<<9)+e];
  for (int e=tid; e<512; e+=256){ int wv=e>>6, j=e&63; fw_lds[wv*65+j] = Fw[((size_t)b<<9)+e]; }
  __syncthreads();
  // stage 1: t[g][j][c] = sum_i fh[i][g]*img[i][j][c], all 8 g in registers
  int o = tid&3, j = tid>>2;    // c-octet within half, column j
  float acc[8][8];              // [g][c]
  #pragma unroll
  for (int g=0;g<8;g++)
    #pragma unroll
    for (int cc=0;cc<8;cc++) acc[g][cc]=0.f;
  const u16* ip = im + (size_t)b*262144 + (size_t)j*64 + ch*32 + o*8;
  #pragma unroll 4
  for (int i=0;i<64;i++){
    uint4 v = *(const uint4*)(ip + (size_t)i*4096);
    float f[8];
    f[0]=bf2f((u16)(v.x&0xffff)); f[1]=bf2f((u16)(v.x>>16));
    f[2]=bf2f((u16)(v.y&0xffff)); f[3]=bf2f((u16)(v.y>>16));
    f[4]=bf2f((u16)(v.z&0xffff)); f[5]=bf2f((u16)(v.z>>16));
    f[6]=bf2f((u16)(v.w&0xffff)); f[7]=bf2f((u16)(v.w>>16));
    #pragma unroll
    for (int g=0;g<8;g++){
      float fg = fh_lds[i*8+g];
      #pragma unroll
      for (int cc=0;cc<8;cc++) acc[g][cc] += fg*f[cc];
    }
  }
  // stage 2 in two g-halves (t_lds holds 4 g at a time; keeps LDS < 64KB)
  u16* fb = flatbf + ((size_t)b<<12);
  #pragma unroll
  for (int gh=0; gh<2; gh++){
    if (gh) __syncthreads();   // prev half fully read
    #pragma unroll
    for (int g=0;g<4;g++){
      float* tp = &t_lds[g*TG + j*TJ + o*8];
      #pragma unroll
      for (int cc=0;cc<8;cc++) tp[cc] = acc[gh*4+g][cc];
    }
    __syncthreads();
    // gl[g][w][c] = sum_j fw[w][j] * t[g][j][c]; thread -> (o2: 4ch, wv, gg)
    int o2 = tid&7, wv = (tid>>3)&7, gg = tid>>6;   // gg in [0,4)
    f32x4 outv = (f32x4){0.f,0.f,0.f,0.f};
    for (int jj=0; jj<64; jj++){
      float fwv = fw_lds[wv*65+jj];
      f32x4 tv = *(const f32x4*)&t_lds[gg*TG + jj*TJ + o2*4];
      outv[0] += fwv*tv[0]; outv[1] += fwv*tv[1];
      outv[2] += fwv*tv[2]; outv[3] += fwv*tv[3];
    }
    int g_glob = gh*4 + gg;
    #pragma unroll
    for (int cc=0;cc<4;cc++)
      fb[(ch*32 + o2*4 + cc)*64 + g_glob*8 + wv] = f2bf(outv[cc]);
  }
}

// phase M: gates GEMM flat(128x4096)@wg^T -> part[ks](128x512). blk in [0,256): (nt=blk>>4, ks=blk&15).
__device__ void gemm_phase(int blk, int tid, const u16* __restrict__ flatbf,
                           const u16* __restrict__ wg, float* __restrict__ part)
{
  int nt = blk>>4, ks = blk&15;
  int n0 = nt*32, kc0 = ks*8;
  int wv = tid>>6, lane = tid&63;
  int m = lane&15, q = lane>>4;
  int m0 = wv*32;
  f32x4 acc[2][2];
  #pragma unroll
  for (int a=0;a<2;a++)
    #pragma unroll
    for (int bb=0;bb<2;bb++) acc[a][bb] = (f32x4){0.f,0.f,0.f,0.f};
  #pragma unroll
  for (int kc=0; kc<8; kc++){
    int kcc = kc0 + kc;
    bf16x8 a0 = *(const bf16x8*)(flatbf + ((size_t)(m0+m)<<12)    + kcc*32 + q*8);
    bf16x8 a1 = *(const bf16x8*)(flatbf + ((size_t)(m0+16+m)<<12) + kcc*32 + q*8);
    bf16x8 b0 = *(const bf16x8*)(wg + ((size_t)(kcc*512 + n0 + m))*32 + q*8);
    bf16x8 b1 = *(const bf16x8*)(wg + ((size_t)(kcc*512 + n0 + 16 + m))*32 + q*8);
    acc[0][0] = __builtin_amdgcn_mfma_f32_16x16x32_bf16(a0, b0, acc[0][0], 0,0,0);
    acc[0][1] = __builtin_amdgcn_mfma_f32_16x16x32_bf16(a0, b1, acc[0][1], 0,0,0);
    acc[1][0] = __builtin_amdgcn_mfma_f32_16x16x32_bf16(a1, b0, acc[1][0], 0,0,0);
    acc[1][1] = __builtin_amdgcn_mfma_f32_16x16x32_bf16(a1, b1, acc[1][1], 0,0,0);
  }
  float* pp = part + (size_t)ks*65536;
  #pragma unroll
  for (int mt=0;mt<2;mt++)
    #pragma unroll
    for (int ntt=0;ntt<2;ntt++)
      #pragma unroll
      for (int r=0;r<4;r++)
        pp[(size_t)(m0 + mt*16 + q*4 + r)*512 + n0 + ntt*16 + m] = acc[mt][ntt][r];
}

// phase L: LSTM update + next-turn params. b in [0,128). works with >=128 threads.
__device__ void lstm_phase(int b, int tid,
                           float* __restrict__ Hx, float* __restrict__ Cx,
                           const float* __restrict__ part, const float* __restrict__ whhT,
                           const float* __restrict__ bih, const float* __restrict__ bhh,
                           const float* __restrict__ gw, const float* __restrict__ gb,
                           float* __restrict__ FhT, float* __restrict__ Fw, float* smem)
{
  float* hs  = smem;
  float* hs2 = smem + 128;
  if (tid < 128) hs[tid] = Hx[b*128+tid];
  __syncthreads();
  if (tid < 128){
    int hid = tid;
    float g4[4];
    #pragma unroll
    for (int qd=0; qd<4; qd++){
      int n = qd*128 + hid;
      float acc = bih[n] + bhh[n];
      const float* pp = part + (size_t)b*512 + n;
      #pragma unroll 8
      for (int ks=0; ks<16; ks++) acc += pp[(size_t)ks*65536];
      const float* wp = whhT + n;
      #pragma unroll 8
      for (int k=0;k<128;k++) acc += hs[k]*wp[(size_t)k*512];
      g4[qd] = acc;
    }
    float cx = Cx[b*128+hid];
    float cn = sigf(g4[1])*cx + sigf(g4[0])*tanhf(g4[2]);
    float hn = sigf(g4[3])*tanhf(cn);
    Cx[b*128+hid] = cn;
    Hx[b*128+hid] = hn;
    hs2[hid] = hn;
  }
  __syncthreads();
  if (tid < 64)
    compute_params_lane(b, tid, hs2[tid], hs2[64+tid], gw, gb, FhT, Fw);
}

// ---------------- fused 16-turn recurrent loop (cooperative, 256 blocks x 256 threads) ----------------
__global__ __launch_bounds__(256) void turns_kernel(
    const u16* __restrict__ gimgT, const u16* __restrict__ gimgS,
    const u16* __restrict__ wg,   const float* __restrict__ whhT,
    const float* __restrict__ bih, const float* __restrict__ bhh,
    const float* __restrict__ gw,  const float* __restrict__ gb,
    float* __restrict__ Hx, float* __restrict__ Cx,
    float* __restrict__ FhT, float* __restrict__ Fw,
    u16* __restrict__ flatbf, float* __restrict__ part)
{
  cg::grid_group gridg = cg::this_grid();
  int blk = blockIdx.x, tid = threadIdx.x;
  __shared__ __align__(16) float smem[SMEM_FLOATS];   // 37.9 KB

  // phase 0: initial params (Hx = 0, already memset)
  if (blk < 128 && tid < 64)
    compute_params_lane(blk, tid, Hx[blk*128+tid], Hx[blk*128+64+tid], gw, gb, FhT, Fw);
  gridg.sync();

  for (int t=0; t<16; t++){
    const u16* im = (t&1)? gimgS : gimgT;
    glimpse_phase(blk, tid, im, FhT, Fw, flatbf, smem);
    gridg.sync();
    gemm_phase(blk, tid, flatbf, wg, part);
    gridg.sync();
    if (blk < 128)
      lstm_phase(blk, tid, Hx, Cx, part, whhT, bih, bhh, gw, gb, FhT, Fw, smem);
    gridg.sync();
  }
}

// ---------------- fallback standalone phase kernels (identical math) ----------------
__global__ __launch_bounds__(256) void glimpse_phase_kernel(
    const u16* __restrict__ im, const float* __restrict__ FhT,
    const float* __restrict__ Fw, u16* __restrict__ flatbf)
{
  __shared__ __align__(16) float smem[SMEM_FLOATS];
  glimpse_phase(blockIdx.x, threadIdx.x, im, FhT, Fw, flatbf, smem);
}

__global__ __launch_bounds__(256) void gemm_phase_kernel(
    const u16* __restrict__ flatbf, const u16* __restrict__ wg, float* __restrict__ part)
{
  gemm_phase(blockIdx.x, threadIdx.x, flatbf, wg, part);
}

__global__ __launch_bounds__(128) void lstm_phase_kernel(
    float* __restrict__ Hx, float* __restrict__ Cx,
    const float* __restrict__ part, const float* __restrict__ whhT,
    const float* __restrict__ bih, const float* __restrict__ bhh,
    const float* __restrict__ gw, const float* __restrict__ gb,
    float* __restrict__ FhT, float* __restrict__ Fw)
{
  __shared__ float smem[256];
  lstm_phase(blockIdx.x, threadIdx.x, Hx, Cx, part, whhT, bih, bhh, gw, gb, FhT, Fw, smem);
}

extern "C" void kernel_launch(void* const* d_in, const int* in_sizes, int n_in,
                              void* d_out, int out_size, void* d_ws, size_t ws_size,
                              hipStream_t stream)
{
  const float* imgp = (const float*)d_in[0];
  const float* w1  = (const float*)d_in[1];
  // d_in[2] = conv1 bias: cancels through bn1 -> unused
  const float* g1  = (const float*)d_in[3];
  const float* be1 = (const float*)d_in[4];
  const float* w2  = (const float*)d_in[5];
  // d_in[6] = conv2 bias: cancels through bn2 -> unused
  const float* g2  = (const float*)d_in[7];
  const float* be2 = (const float*)d_in[8];
  const float* wih = (const float*)d_in[9];
  const float* whh = (const float*)d_in[10];
  const float* bih = (const float*)d_in[11];
  const float* bhh = (const float*)d_in[12];
  const float* gw  = (const float*)d_in[13];
  const float* gb  = (const float*)d_in[14];

  char* ws = (char*)d_ws;
  u16* imgT    = (u16*)(ws + 0);           // test resblock out, NHWC bf16 (B,64,64,64c)
  u16* imgS    = (u16*)(ws + 67108864);    // support
  u16* tmp     = (u16*)(ws + 134217728);   // conv1/bn1 intermediate (dead after conv phase)
  // turn-loop scratch overlays tmp:
  float* FhT     = (float*)(ws + 134217728); // (B,64,8)
  float* Fw      = (float*)(ws + 134479872); // (B,8,64)
  u16*   flatbf  = (u16*)  (ws + 134742016); // (B,4096) bf16
  float* part    = (float*)(ws + 135790592); // (16,128,512) f32
  // persistent region (outside tmp):
  u16*   wpack   = (u16*)  (ws + 201326592); // conv2 weights (9,2,64,32) bf16
  float* Hx      = (float*)(ws + 201400320);
  float* Cx      = (float*)(ws + 201465856);
  float* stats   = (float*)(ws + 201531392); // 4 regions x 128 f32
  float* whhT    = (float*)(ws + 201533440); // (128,512)
  u16*   wg      = (u16*)  (ws + 201795584); // (128,512,32) bf16 gate weights
  if (ws_size < 205989888ull) return;

  hipMemsetAsync(Hx, 0, 65536+65536+2048, stream);   // Hx, Cx, stats contiguous
  wpack_kernel<<<144,256,0,stream>>>(w2, wpack);
  wgpack_kernel<<<8192,256,0,stream>>>(wih, wg);
  transpose_whh_kernel<<<256,256,0,stream>>>(whh, whhT);

  for (int s=0; s<2; s++){
    int ch = (s==0)?1:0;                   // s=0: TEST (channel 1), s=1: SUPPORT (channel 0)
    u16* dst = (s==0)? imgT : imgS;
    conv1_nhwc_kernel<<<dim3(16,128),256,0,stream>>>(imgp, ch, w1, tmp);
    stats_nhwc_kernel<<<512,256,0,stream>>>(tmp, stats + 128*(2*s));
    bnapply_nhwc_kernel<<<16384,256,0,stream>>>(tmp, stats + 128*(2*s), g1, be1, imgp, ch, 0);
    conv2_mfma_kernel<<<dim3(32,128),256,0,stream>>>(tmp, wpack, dst);
    stats_nhwc_kernel<<<512,256,0,stream>>>(dst, stats + 128*(2*s+1));
    bnapply_nhwc_kernel<<<16384,256,0,stream>>>(dst, stats + 128*(2*s+1), g2, be2, imgp, ch, 1);
  }

  // fused 16-turn recurrent loop (cooperative), with per-phase fallback if launch is rejected
  {
    const u16* a0 = imgT; const u16* a1 = imgS; const u16* a2 = wg;
    const float* a3 = whhT; const float* a4 = bih; const float* a5 = bhh;
    const float* a6 = gw; const float* a7 = gb;
    float* a8 = Hx; float* a9 = Cx; float* a10 = FhT; float* a11 = Fw;
    u16* a12 = flatbf; float* a13 = part;
    void* kargs[] = { &a0,&a1,&a2,&a3,&a4,&a5,&a6,&a7,&a8,&a9,&a10,&a11,&a12,&a13 };
    hipError_t cerr = hipLaunchCooperativeKernel((void*)turns_kernel, dim3(256), dim3(256),
                                                 kargs, 0, stream);
    if (cerr != hipSuccess){
      params_kernel<<<128,64,0,stream>>>(Hx, gw, gb, FhT, Fw);
      for (int t=0; t<16; t++){
        const u16* im = (t&1)? imgS : imgT;
        glimpse_phase_kernel<<<256,256,0,stream>>>(im, FhT, Fw, flatbf);
        gemm_phase_kernel<<<256,256,0,stream>>>(flatbf, wg, part);
        lstm_phase_kernel<<<128,128,0,stream>>>(Hx, Cx, part, whhT, bih, bhh, gw, gb, FhT, Fw);
      }
    }
  }

  hipMemcpyAsync(d_out, Hx, (size_t)16384*4, hipMemcpyDeviceToDevice, stream);
}

// Round 6
// 2383.473 us; speedup vs baseline: 1.3060x; 1.3060x over previous
//
#include <hip/hip_runtime.h>
#include <math.h>

typedef unsigned short u16;
typedef unsigned int u32;
typedef short bf16x8 __attribute__((ext_vector_type(8)));
typedef float f32x4 __attribute__((ext_vector_type(4)));

#define PI_F 3.14159265358979323846f

static __device__ __forceinline__ float bf2f(u16 u){ union{u32 i; float f;} v; v.i=((u32)u)<<16; return v.f; }
static __device__ __forceinline__ u16 f2bf(float f){ union{u32 i; float f;} v; v.f=f; u32 r=v.i+0x7fffu+((v.i>>16)&1u); return (u16)(r>>16); }
static __device__ __forceinline__ float sigf(float x){ return 1.0f/(1.0f+expf(-x)); }

// device(agent)-scope coherent scalar ops: cross-XCD producer/consumer without L2 flush
static __device__ __forceinline__ void stga(float* p, float v){ __hip_atomic_store(p, v, __ATOMIC_RELAXED, __HIP_MEMORY_SCOPE_AGENT); }
static __device__ __forceinline__ float ldga(const float* p){ return __hip_atomic_load(p, __ATOMIC_RELAXED, __HIP_MEMORY_SCOPE_AGENT); }

// lightweight grid barrier: monotone counter, release-arrive + relaxed spin + one acquire
static __device__ __forceinline__ void gbar(u32* cnt, u32 bound){
  __syncthreads();
  if (threadIdx.x==0){
    __hip_atomic_fetch_add(cnt, 1u, __ATOMIC_RELEASE, __HIP_MEMORY_SCOPE_AGENT);
    while (__hip_atomic_load(cnt, __ATOMIC_RELAXED, __HIP_MEMORY_SCOPE_AGENT) < bound)
      __builtin_amdgcn_s_sleep(8);
    (void)__hip_atomic_load(cnt, __ATOMIC_ACQUIRE, __HIP_MEMORY_SCOPE_AGENT);
  }
  __syncthreads();
}

// ---------------- pack conv2 weights to bf16 fragment order: wpack[tap][chunk][oc][k=q*8+j] ----------------
__global__ __launch_bounds__(256) void wpack_kernel(const float* __restrict__ w2, u16* __restrict__ wpack)
{
  int e = blockIdx.x*256 + threadIdx.x;   // 36864 = 9*2*64*32
  if (e >= 36864) return;
  int k  = e & 31;
  int oc = (e>>5) & 63;
  int tc = e>>11;            // 0..17
  int tap = tc>>1, c = tc&1;
  int ic = c*32 + k;
  wpack[e] = f2bf(w2[(size_t)(oc*64 + ic)*9 + tap]);
}

// ---------------- pack gate weights wih (512x4096) to bf16 fragment order: wg[kc][n][kidx] ----------------
__global__ __launch_bounds__(256) void wgpack_kernel(const float* __restrict__ wih, u16* __restrict__ wg)
{
  int e = blockIdx.x*256 + threadIdx.x;   // 2097152 = 128*512*32
  int kidx = e & 31;
  int n  = (e>>5) & 511;
  int kc = e>>14;           // 0..127
  wg[e] = f2bf(wih[(size_t)n*4096 + kc*32 + kidx]);
}

// ---------------- conv1: img (B,2,64,64)[ch] f32 -> bf16 NHWC (B,64,64,64ch) ----------------
__global__ __launch_bounds__(256) void conv1_nhwc_kernel(
    const float* __restrict__ imgp, int ch,
    const float* __restrict__ w1, u16* __restrict__ out)
{
  int b = blockIdx.y, tile = blockIdx.x;
  int ty0 = (tile>>2)<<4, tx0 = (tile&3)<<4;
  int tid = threadIdx.x;
  __shared__ float patch[18*18];
  __shared__ float wsm[576];
  const float* ib = imgp + (((size_t)b*2 + ch)<<12);
  for (int e=tid; e<324; e+=256){
    int py = e/18, px = e - py*18;
    int gy = ty0+py-1, gx = tx0+px-1;
    float v = 0.f;
    if (gy>=0 && gy<64 && gx>=0 && gx<64) v = ib[(gy<<6)+gx];
    patch[e] = v;
  }
  for (int e=tid; e<576; e+=256) wsm[e] = w1[e];
  __syncthreads();
  int ty = tid>>4, tx = tid&15;
  float p[9];
  #pragma unroll
  for (int ky=0;ky<3;ky++)
    #pragma unroll
    for (int kx=0;kx<3;kx++) p[ky*3+kx] = patch[(ty+ky)*18 + tx+kx];
  u16* ob = out + ((((size_t)b<<12) + ((size_t)(ty0+ty)<<6) + (size_t)(tx0+tx))<<6);
  #pragma unroll
  for (int ocq=0; ocq<8; ocq++){
    u32 w4[4];
    #pragma unroll
    for (int pair=0; pair<4; pair++){
      float a0=0.f, a1=0.f;
      int oc0 = ocq*8 + pair*2;
      #pragma unroll
      for (int k=0;k<9;k++){ a0 += wsm[oc0*9+k]*p[k]; a1 += wsm[(oc0+1)*9+k]*p[k]; }
      w4[pair] = (u32)f2bf(a0) | ((u32)f2bf(a1)<<16);
    }
    ((uint4*)ob)[ocq] = make_uint4(w4[0],w4[1],w4[2],w4[3]);
  }
}

// ---------------- per-channel sum/sumsq over NHWC bf16 buf ----------------
__global__ __launch_bounds__(256) void stats_nhwc_kernel(const u16* __restrict__ buf, float* __restrict__ st)
{
  int tid = threadIdx.x;
  int c8 = (tid&7)*8;
  int pg = tid>>3;                 // 0..31
  size_t p0 = (size_t)blockIdx.x*1024 + pg;
  float s[8], s2[8];
  #pragma unroll
  for (int k=0;k<8;k++){ s[k]=0.f; s2[k]=0.f; }
  for (int it=0; it<32; it++){
    size_t p = p0 + (size_t)it*32;
    uint4 v = *(const uint4*)(buf + (p<<6) + c8);
    u32 rw[4] = {v.x,v.y,v.z,v.w};
    #pragma unroll
    for (int d=0; d<4; d++){
      float f0 = bf2f((u16)(rw[d]&0xffff));
      float f1 = bf2f((u16)(rw[d]>>16));
      s[d*2]   += f0; s2[d*2]   += f0*f0;
      s[d*2+1] += f1; s2[d*2+1] += f1*f1;
    }
  }
  #pragma unroll
  for (int off=32; off>=8; off>>=1){
    #pragma unroll
    for (int k=0;k<8;k++){ s[k] += __shfl_down(s[k], off, 64); s2[k] += __shfl_down(s2[k], off, 64); }
  }
  __shared__ float sm[128];
  if (tid<128) sm[tid]=0.f;
  __syncthreads();
  if ((tid&63) < 8){
    int cb = tid&7;
    #pragma unroll
    for (int k=0;k<8;k++){
      atomicAdd(&sm[cb*8+k], s[k]);
      atomicAdd(&sm[64+cb*8+k], s2[k]);
    }
  }
  __syncthreads();
  if (tid<128) atomicAdd(&st[tid], sm[tid]);
}

// ---------------- BN apply (+optional residual) + ReLU, in-place on NHWC bf16 ----------------
__global__ __launch_bounds__(256) void bnapply_nhwc_kernel(
    u16* __restrict__ buf, const float* __restrict__ st,
    const float* __restrict__ gam, const float* __restrict__ bet,
    const float* __restrict__ imgp, int ch, int addres)
{
  size_t i8 = (size_t)blockIdx.x*256 + threadIdx.x;
  size_t e0 = i8*8;
  int cb = (int)(e0&63);
  size_t pos = e0>>6;
  const float invN = 1.0f/524288.0f;
  float res = 0.f;
  if (addres){
    int b = (int)(pos>>12);
    res = imgp[(((size_t)(b*2+ch))<<12) + (pos&4095)];
  }
  uint4 raw = *(const uint4*)(buf+e0);
  u32 rw[4] = {raw.x, raw.y, raw.z, raw.w};
  u32 ow[4];
  #pragma unroll
  for (int d=0; d<4; d++){
    u32 o = 0;
    #pragma unroll
    for (int h=0; h<2; h++){
      int c = cb + d*2 + h;
      float mean = st[c]*invN;
      float var  = st[64+c]*invN - mean*mean;
      float sc = gam[c]*rsqrtf(var+1e-5f);
      float sh = bet[c] - mean*sc;
      float v = bf2f((u16)((rw[d]>>(16*h))&0xffff))*sc + sh + res;
      v = fmaxf(v, 0.f);
      o |= ((u32)f2bf(v)) << (16*h);
    }
    ow[d] = o;
  }
  *(uint4*)(buf+e0) = make_uint4(ow[0],ow[1],ow[2],ow[3]);
}

// ---------------- conv2 MFMA: NHWC bf16 -> NHWC bf16 ----------------
__global__ __launch_bounds__(256) void conv2_mfma_kernel(
    const u16* __restrict__ in, const u16* __restrict__ wpack, u16* __restrict__ out)
{
  int b = blockIdx.y, tile = blockIdx.x;     // 32 tiles: 8 y-tiles x 4 x-tiles
  int y0 = (tile>>2)*8, x0 = (tile&3)*16;
  int tid = threadIdx.x;
  int w = tid>>6, lane = tid&63;
  int m = lane&15, q = lane>>4;

  __shared__ __align__(16) u16 patch[11520];  // [py10][cq8][px18][j8]

  for (int e=tid; e<1440; e+=256){
    int py = e/144; int rem = e - py*144;
    int px = rem>>3, cq = rem&7;
    int y = y0-1+py, x = x0-1+px;
    uint4 v = make_uint4(0,0,0,0);
    if (y>=0 && y<64 && x>=0 && x<64)
      v = *(const uint4*)(in + ((((size_t)b<<12) + ((size_t)y<<6) + (size_t)x)<<6) + cq*8);
    *(uint4*)(patch + ((((py<<3)+cq)*18 + px)<<3)) = v;
  }
  __syncthreads();

  f32x4 acc[2][4];
  #pragma unroll
  for (int mt=0;mt<2;mt++)
    #pragma unroll
    for (int nt=0;nt<4;nt++) acc[mt][nt] = (f32x4){0.f,0.f,0.f,0.f};

  #pragma unroll
  for (int tap=0; tap<9; tap++){
    const int dy = tap/3, dx = tap%3;
    #pragma unroll
    for (int c=0; c<2; c++){
      const int kk = tap*2 + c;
      bf16x8 bw[4];
      #pragma unroll
      for (int nt=0; nt<4; nt++)
        bw[nt] = *(const bf16x8*)(wpack + (size_t)(kk*64 + nt*16 + m)*32 + q*8);
      #pragma unroll
      for (int mt=0; mt<2; mt++){
        int py = 2*w + mt + dy;
        bf16x8 av = *(const bf16x8*)(patch + ((((py<<3) + (c<<2) + q)*18 + (m+dx))<<3));
        #pragma unroll
        for (int nt=0; nt<4; nt++)
          acc[mt][nt] = __builtin_amdgcn_mfma_f32_16x16x32_bf16(av, bw[nt], acc[mt][nt], 0,0,0);
      }
    }
  }
  __syncthreads();
  u16* etile = patch;                        // reuse: 128px x 64oc bf16 = 16KB
  #pragma unroll
  for (int mt=0; mt<2; mt++){
    int lp = (2*w+mt)*16 + q*4;
    #pragma unroll
    for (int nt=0; nt<4; nt++)
      #pragma unroll
      for (int r=0; r<4; r++)
        etile[(lp+r)*64 + nt*16 + m] = f2bf(acc[mt][nt][r]);
  }
  __syncthreads();
  int lp = tid>>1, half = tid&1;
  int y = y0 + (lp>>4), x = x0 + (lp&15);
  uint4* gdst = (uint4*)(out + ((((size_t)b<<12) + ((size_t)y<<6) + (size_t)x)<<6) + half*32);
  const uint4* lsrc = (const uint4*)(etile + lp*64 + half*32);
  gdst[0] = lsrc[0];
  gdst[1] = lsrc[1];
  gdst[2] = lsrc[2];
  gdst[3] = lsrc[3];
}

// ---------------- glimpser linear + tanh + Cauchy filterbanks (per-lane helper, lane<64) ----------------
// FhT/Fw written with agent-scope stores (consumed cross-phase via agent loads)
__device__ __forceinline__ void compute_params_lane(
    int b, int lane, float h0, float h1,
    const float* __restrict__ gw, const float* __restrict__ gb,
    float* __restrict__ FhT, float* __restrict__ Fw)
{
  float gpv[3];
  #pragma unroll
  for (int k=0;k<3;k++){
    float p = h0*gw[k*128+lane] + h1*gw[k*128+64+lane];
    #pragma unroll
    for (int off=32; off>0; off>>=1) p += __shfl_down(p, off, 64);
    float tot = __shfl(p, 0, 64);
    gpv[k] = tanhf(tot + gb[k]);
  }
  float ad = fabsf(gpv[2]);
  float delta = 8.0f*(1.0f-ad);
  float gamma = expf(1.0f-2.0f*ad);
  float inv_pg = 1.0f/(PI_F*gamma);
  float fi = (float)lane;
  float ctr = 31.5f*(gpv[0]+1.0f);
  float* o = FhT + (((size_t)b<<6) + lane)*8;
  #pragma unroll
  for (int g=0; g<8; g++){
    float mu = ctr + delta*((float)g - 3.5f);
    float u = (fi - mu)/gamma;
    float f = inv_pg/(1.0f+u*u);
    float s = f;
    #pragma unroll
    for (int off=32; off>0; off>>=1) s += __shfl_down(s, off, 64);
    s = __shfl(s, 0, 64);
    stga(o+g, f/(s + 1e-4f));
  }
  ctr = 31.5f*(gpv[1]+1.0f);
  #pragma unroll
  for (int wv=0; wv<8; wv++){
    float mu = ctr + delta*((float)wv - 3.5f);
    float u = (fi - mu)/gamma;
    float f = inv_pg/(1.0f+u*u);
    float s = f;
    #pragma unroll
    for (int off=32; off>0; off>>=1) s += __shfl_down(s, off, 64);
    s = __shfl(s, 0, 64);
    stga(&Fw[(((size_t)b<<3)+wv)*64 + lane], f/(s + 1e-4f));
  }
}

__global__ __launch_bounds__(64) void params_kernel(
    const float* __restrict__ Hx,
    const float* __restrict__ gw, const float* __restrict__ gb,
    float* __restrict__ FhT, float* __restrict__ Fw)
{
  int b = blockIdx.x, lane = threadIdx.x;
  compute_params_lane(b, lane, Hx[b*128+lane], Hx[b*128+64+lane], gw, gb, FhT, Fw);
}

__global__ __launch_bounds__(256) void transpose_whh_kernel(
    const float* __restrict__ whh, float* __restrict__ whhT)
{
  int idx = blockIdx.x*256 + threadIdx.x; // 65536 total
  int k = idx>>9, n = idx&511;
  whhT[idx] = whh[n*128 + k];
}

// ================= turn-loop phase device functions =================
#define TJ 33      // j-stride in t_lds
#define TG 2113    // g-stride in t_lds (64*33+1)
#define SMEM_FLOATS 9488   // 512 + 520 + 4*2113 = 9484, rounded

// phase G: glimpse. blk in [0,256): (b = blk>>1, ch-half = blk&1). 256 threads.
// output: flatf[b][k] f32 via agent stores
__device__ void glimpse_phase(int blk, int tid, const u16* __restrict__ im,
                              const float* __restrict__ FhT, const float* __restrict__ Fw,
                              float* __restrict__ flatf, float* smem)
{
  float* fh_lds = smem;          // 512: [i][g]
  float* fw_lds = smem + 512;    // 8*65: [w][j] padded
  float* t_lds  = smem + 1032;   // 4*TG: [g-half][j*TJ + c]
  int b = blk>>1, ch = blk&1;
  for (int e=tid; e<512; e+=256) fh_lds[e] = ldga(FhT + ((size_t)b<<9) + e);
  for (int e=tid; e<512; e+=256){ int wv=e>>6, j=e&63; fw_lds[wv*65+j] = ldga(Fw + ((size_t)b<<9) + e); }
  __syncthreads();
  // stage 1: t[g][j][c] = sum_i fh[i][g]*img[i][j][c], all 8 g in registers
  int o = tid&3, j = tid>>2;    // c-octet within half, column j
  float acc[8][8];              // [g][c]
  #pragma unroll
  for (int g=0;g<8;g++)
    #pragma unroll
    for (int cc=0;cc<8;cc++) acc[g][cc]=0.f;
  const u16* ip = im + (size_t)b*262144 + (size_t)j*64 + ch*32 + o*8;
  #pragma unroll 4
  for (int i=0;i<64;i++){
    uint4 v = *(const uint4*)(ip + (size_t)i*4096);
    float f[8];
    f[0]=bf2f((u16)(v.x&0xffff)); f[1]=bf2f((u16)(v.x>>16));
    f[2]=bf2f((u16)(v.y&0xffff)); f[3]=bf2f((u16)(v.y>>16));
    f[4]=bf2f((u16)(v.z&0xffff)); f[5]=bf2f((u16)(v.z>>16));
    f[6]=bf2f((u16)(v.w&0xffff)); f[7]=bf2f((u16)(v.w>>16));
    #pragma unroll
    for (int g=0;g<8;g++){
      float fg = fh_lds[i*8+g];
      #pragma unroll
      for (int cc=0;cc<8;cc++) acc[g][cc] += fg*f[cc];
    }
  }
  // stage 2 in two g-halves (t_lds holds 4 g at a time)
  float* fbf = flatf + ((size_t)b<<12);
  #pragma unroll
  for (int gh=0; gh<2; gh++){
    if (gh) __syncthreads();   // prev half fully read
    #pragma unroll
    for (int g=0;g<4;g++){
      float* tp = &t_lds[g*TG + j*TJ + o*8];
      #pragma unroll
      for (int cc=0;cc<8;cc++) tp[cc] = acc[gh*4+g][cc];
    }
    __syncthreads();
    // gl[g][w][c] = sum_j fw[w][j] * t[g][j][c]; thread -> (o2: 4ch, wv, gg)
    int o2 = tid&7, wv = (tid>>3)&7, gg = tid>>6;   // gg in [0,4)
    f32x4 outv = (f32x4){0.f,0.f,0.f,0.f};
    for (int jj=0; jj<64; jj++){
      float fwv = fw_lds[wv*65+jj];
      f32x4 tv = *(const f32x4*)&t_lds[gg*TG + jj*TJ + o2*4];
      outv[0] += fwv*tv[0]; outv[1] += fwv*tv[1];
      outv[2] += fwv*tv[2]; outv[3] += fwv*tv[3];
    }
    int g_glob = gh*4 + gg;
    #pragma unroll
    for (int cc=0;cc<4;cc++)
      stga(fbf + (ch*32 + o2*4 + cc)*64 + g_glob*8 + wv, outv[cc]);
  }
}

// phase M: gates GEMM flat(128x4096)@wg^T -> part[ks](128x512). blk: (nt=blk>>4, ks=blk&15).
__device__ void gemm_phase(int blk, int tid, const float* __restrict__ flatf,
                           const u16* __restrict__ wg, float* __restrict__ part)
{
  int nt = blk>>4, ks = blk&15;
  int n0 = nt*32, kc0 = ks*8;
  int wv = tid>>6, lane = tid&63;
  int m = lane&15, q = lane>>4;
  int m0 = wv*32;
  f32x4 acc[2][2];
  #pragma unroll
  for (int a=0;a<2;a++)
    #pragma unroll
    for (int bb=0;bb<2;bb++) acc[a][bb] = (f32x4){0.f,0.f,0.f,0.f};
  #pragma unroll
  for (int kc=0; kc<8; kc++){
    int kcc = kc0 + kc;
    float af0[8], af1[8];
    #pragma unroll
    for (int t8=0;t8<8;t8++){
      af0[t8] = ldga(flatf + ((size_t)(m0+m)<<12)    + kcc*32 + q*8 + t8);
      af1[t8] = ldga(flatf + ((size_t)(m0+16+m)<<12) + kcc*32 + q*8 + t8);
    }
    bf16x8 a0, a1;
    #pragma unroll
    for (int t8=0;t8<8;t8++){ a0[t8] = (short)f2bf(af0[t8]); a1[t8] = (short)f2bf(af1[t8]); }
    bf16x8 b0 = *(const bf16x8*)(wg + ((size_t)(kcc*512 + n0 + m))*32 + q*8);
    bf16x8 b1 = *(const bf16x8*)(wg + ((size_t)(kcc*512 + n0 + 16 + m))*32 + q*8);
    acc[0][0] = __builtin_amdgcn_mfma_f32_16x16x32_bf16(a0, b0, acc[0][0], 0,0,0);
    acc[0][1] = __builtin_amdgcn_mfma_f32_16x16x32_bf16(a0, b1, acc[0][1], 0,0,0);
    acc[1][0] = __builtin_amdgcn_mfma_f32_16x16x32_bf16(a1, b0, acc[1][0], 0,0,0);
    acc[1][1] = __builtin_amdgcn_mfma_f32_16x16x32_bf16(a1, b1, acc[1][1], 0,0,0);
  }
  float* pp = part + (size_t)ks*65536;
  #pragma unroll
  for (int mt=0;mt<2;mt++)
    #pragma unroll
    for (int ntt=0;ntt<2;ntt++)
      #pragma unroll
      for (int r=0;r<4;r++)
        stga(pp + (size_t)(m0 + mt*16 + q*4 + r)*512 + n0 + ntt*16 + m, acc[mt][ntt][r]);
}

// ---------------- fused 16-turn recurrent loop (cooperative, 256 blocks x 256 threads) ----------------
__global__ __launch_bounds__(256) void turns_kernel(
    const u16* __restrict__ gimgT, const u16* __restrict__ gimgS,
    const u16* __restrict__ wg,   const float* __restrict__ whhT,
    const float* __restrict__ bih, const float* __restrict__ bhh,
    const float* __restrict__ gw,  const float* __restrict__ gb,
    float* __restrict__ Hx,
    float* __restrict__ FhT, float* __restrict__ Fw,
    float* __restrict__ flatf, float* __restrict__ part,
    u32* __restrict__ bar)
{
  int blk = blockIdx.x, tid = threadIdx.x;
  __shared__ __align__(16) float smem[SMEM_FLOATS];   // ~37.9 KB, per-phase scratch
  __shared__ float hxs[128], cxs[128];                // persistent LSTM state (per b = blk>>1)
  int b = blk>>1;

  if (tid < 128){ hxs[tid] = 0.f; cxs[tid] = 0.f; }
  // initial params from Hx = 0 (state starts at zero)
  if (tid < 64)
    compute_params_lane(b, tid, 0.f, 0.f, gw, gb, FhT, Fw);
  __syncthreads();

  u32 bseq = 0;
  for (int t=0; t<16; t++){
    const u16* im = (t&1)? gimgS : gimgT;

    glimpse_phase(blk, tid, im, FhT, Fw, flatf, smem);
    gbar(bar, 256u*(++bseq));          // flatf ready

    gemm_phase(blk, tid, flatf, wg, part);
    gbar(bar, 256u*(++bseq));          // part ready

    // phase L: LSTM update, duplicated in both blocks of the b-pair (state in LDS)
    if (tid < 128){
      int hid = tid;
      float g4[4];
      #pragma unroll
      for (int qd=0; qd<4; qd++){
        int n = qd*128 + hid;
        float acc = bih[n] + bhh[n];
        const float* pp = part + (size_t)b*512 + n;
        #pragma unroll 8
        for (int ks=0; ks<16; ks++) acc += ldga(pp + (size_t)ks*65536);
        const float* wp = whhT + n;
        #pragma unroll 8
        for (int k=0;k<128;k++) acc += hxs[k]*wp[(size_t)k*512];
        g4[qd] = acc;
      }
      float cx = cxs[hid];
      float cn = sigf(g4[1])*cx + sigf(g4[0])*tanhf(g4[2]);
      float hn = sigf(g4[3])*tanhf(cn);
      __syncthreads();                 // all reads of old hxs complete
      cxs[hid] = cn;
      hxs[hid] = hn;
      Hx[b*128+hid] = hn;              // duplicate identical write (final output)
    } else {
      __syncthreads();
    }
    __syncthreads();                   // hxs updated
    if (tid < 64)
      compute_params_lane(b, tid, hxs[tid], hxs[64+tid], gw, gb, FhT, Fw);
    __syncthreads();                   // drains param stores (vmcnt) before next G reads
  }
}

// ---------------- fallback standalone phase kernels (identical math; used only if coop launch fails) ----------------
__global__ __launch_bounds__(256) void glimpse_phase_kernel(
    const u16* __restrict__ im, const float* __restrict__ FhT,
    const float* __restrict__ Fw, float* __restrict__ flatf)
{
  __shared__ __align__(16) float smem[SMEM_FLOATS];
  glimpse_phase(blockIdx.x, threadIdx.x, im, FhT, Fw, flatf, smem);
}

__global__ __launch_bounds__(256) void gemm_phase_kernel(
    const float* __restrict__ flatf, const u16* __restrict__ wg, float* __restrict__ part)
{
  gemm_phase(blockIdx.x, threadIdx.x, flatf, wg, part);
}

__global__ __launch_bounds__(128) void lstm_phase_kernel(
    float* __restrict__ Hx, float* __restrict__ Cx,
    const float* __restrict__ part, const float* __restrict__ whhT,
    const float* __restrict__ bih, const float* __restrict__ bhh,
    const float* __restrict__ gw, const float* __restrict__ gb,
    float* __restrict__ FhT, float* __restrict__ Fw)
{
  int b = blockIdx.x, tid = threadIdx.x;
  __shared__ float hs[128];
  __shared__ float hs2[128];
  hs[tid] = Hx[b*128+tid];
  __syncthreads();
  float g4[4];
  #pragma unroll
  for (int qd=0; qd<4; qd++){
    int n = qd*128 + tid;
    float acc = bih[n] + bhh[n];
    const float* pp = part + (size_t)b*512 + n;
    #pragma unroll 8
    for (int ks=0; ks<16; ks++) acc += ldga(pp + (size_t)ks*65536);
    const float* wp = whhT + n;
    #pragma unroll 8
    for (int k=0;k<128;k++) acc += hs[k]*wp[(size_t)k*512];
    g4[qd] = acc;
  }
  float cx = Cx[b*128+tid];
  float cn = sigf(g4[1])*cx + sigf(g4[0])*tanhf(g4[2]);
  float hn = sigf(g4[3])*tanhf(cn);
  Cx[b*128+tid] = cn;
  Hx[b*128+tid] = hn;
  hs2[tid] = hn;
  __syncthreads();
  if (tid < 64)
    compute_params_lane(b, tid, hs2[tid], hs2[64+tid], gw, gb, FhT, Fw);
}

extern "C" void kernel_launch(void* const* d_in, const int* in_sizes, int n_in,
                              void* d_out, int out_size, void* d_ws, size_t ws_size,
                              hipStream_t stream)
{
  const float* imgp = (const float*)d_in[0];
  const float* w1  = (const float*)d_in[1];
  // d_in[2] = conv1 bias: cancels through bn1 -> unused
  const float* g1  = (const float*)d_in[3];
  const float* be1 = (const float*)d_in[4];
  const float* w2  = (const float*)d_in[5];
  // d_in[6] = conv2 bias: cancels through bn2 -> unused
  const float* g2  = (const float*)d_in[7];
  const float* be2 = (const float*)d_in[8];
  const float* wih = (const float*)d_in[9];
  const float* whh = (const float*)d_in[10];
  const float* bih = (const float*)d_in[11];
  const float* bhh = (const float*)d_in[12];
  const float* gw  = (const float*)d_in[13];
  const float* gb  = (const float*)d_in[14];

  char* ws = (char*)d_ws;
  u16* imgT    = (u16*)(ws + 0);           // test resblock out, NHWC bf16 (B,64,64,64c)
  u16* imgS    = (u16*)(ws + 67108864);    // support
  u16* tmp     = (u16*)(ws + 134217728);   // conv1/bn1 intermediate (dead after conv phase)
  // turn-loop scratch overlays tmp:
  float* FhT     = (float*)(ws + 134217728); // (B,64,8) f32
  float* Fw      = (float*)(ws + 134479872); // (B,8,64) f32
  float* flatf   = (float*)(ws + 134742016); // (B,4096) f32
  float* part    = (float*)(ws + 136839168); // (16,128,512) f32, ends 141033472
  // persistent region (outside tmp):
  u16*   wpack   = (u16*)  (ws + 201326592); // conv2 weights (9,2,64,32) bf16
  float* Hx      = (float*)(ws + 201400320); // (B,128)
  float* Cx      = (float*)(ws + 201465856); // (B,128) (fallback path only)
  float* stats   = (float*)(ws + 201531392); // 4 regions x 128 f32 (2048 B)
  u32*   bar     = (u32*)  (ws + 201533440); // barrier counter (256 B)
  float* whhT    = (float*)(ws + 201533696); // (128,512)
  u16*   wg      = (u16*)  (ws + 201795840); // (128,512,32) bf16 gate weights
  if (ws_size < 205990144ull) return;

  // zero Hx, Cx, stats, barrier counter (contiguous region)
  hipMemsetAsync(Hx, 0, 65536+65536+2048+256, stream);
  wpack_kernel<<<144,256,0,stream>>>(w2, wpack);
  wgpack_kernel<<<8192,256,0,stream>>>(wih, wg);
  transpose_whh_kernel<<<256,256,0,stream>>>(whh, whhT);

  for (int s=0; s<2; s++){
    int ch = (s==0)?1:0;                   // s=0: TEST (channel 1), s=1: SUPPORT (channel 0)
    u16* dst = (s==0)? imgT : imgS;
    conv1_nhwc_kernel<<<dim3(16,128),256,0,stream>>>(imgp, ch, w1, tmp);
    stats_nhwc_kernel<<<512,256,0,stream>>>(tmp, stats + 128*(2*s));
    bnapply_nhwc_kernel<<<16384,256,0,stream>>>(tmp, stats + 128*(2*s), g1, be1, imgp, ch, 0);
    conv2_mfma_kernel<<<dim3(32,128),256,0,stream>>>(tmp, wpack, dst);
    stats_nhwc_kernel<<<512,256,0,stream>>>(dst, stats + 128*(2*s+1));
    bnapply_nhwc_kernel<<<16384,256,0,stream>>>(dst, stats + 128*(2*s+1), g2, be2, imgp, ch, 1);
  }

  // fused 16-turn recurrent loop (cooperative; custom lightweight grid barrier inside)
  {
    const u16* a0 = imgT; const u16* a1 = imgS; const u16* a2 = wg;
    const float* a3 = whhT; const float* a4 = bih; const float* a5 = bhh;
    const float* a6 = gw; const float* a7 = gb;
    float* a8 = Hx; float* a9 = FhT; float* a10 = Fw;
    float* a11 = flatf; float* a12 = part; u32* a13 = bar;
    void* kargs[] = { &a0,&a1,&a2,&a3,&a4,&a5,&a6,&a7,&a8,&a9,&a10,&a11,&a12,&a13 };
    hipError_t cerr = hipLaunchCooperativeKernel((void*)turns_kernel, dim3(256), dim3(256),
                                                 kargs, 0, stream);
    if (cerr != hipSuccess){
      params_kernel<<<128,64,0,stream>>>(Hx, gw, gb, FhT, Fw);
      for (int t=0; t<16; t++){
        const u16* im = (t&1)? imgS : imgT;
        glimpse_phase_kernel<<<256,256,0,stream>>>(im, FhT, Fw, flatf);
        gemm_phase_kernel<<<256,256,0,stream>>>(flatf, wg, part);
        lstm_phase_kernel<<<128,128,0,stream>>>(Hx, Cx, part, whhT, bih, bhh, gw, gb, FhT, Fw);
      }
    }
  }

  hipMemcpyAsync(d_out, Hx, (size_t)16384*4, hipMemcpyDeviceToDevice, stream);
}